// Round 1
// baseline (760.599 us; speedup 1.0000x reference)
//
#include <hip/hip_runtime.h>

typedef float v2f __attribute__((ext_vector_type(2)));
typedef float v4f __attribute__((ext_vector_type(4)));

#define N_IN   131072
#define K_EMB  1024
#define D_EMB  64
#define QUANT_OFF 1
#define PERP_OFF  (1 + N_IN * D_EMB)      /* 8388609 */
#define ENC_OFF   (PERP_OFF + 1)          /* 8388610: byte offset %16==8 -> float2 stores only */

// ws layout (4-byte units):
//   [0..1023]     counts (u32)
//   [1024]        loss accumulator (f32)
//   [2048..3071]  half squared norms of codes (f32)
//   [4096..69631] Et[d][c]: transposed codebook (R9 fast path only)
#define WS_ET   4096
#define WS_NEED ((size_t)(WS_ET + D_EMB * K_EMB) * 4)

__global__ __launch_bounds__(256) void k_prep(const float* __restrict__ emb,
                                              float* __restrict__ ws,
                                              int buildEt) {
  int k = blockIdx.x * 256 + threadIdx.x;  // grid=4 -> k in [0,1024)
  ((unsigned int*)ws)[k] = 0u;
  if (k == 0) ws[1024] = 0.0f;
  const float* e = emb + (size_t)k * D_EMB;
  double s = 0.0;
  #pragma unroll
  for (int d = 0; d < D_EMB; ++d) {
    float v = e[d];
    s += (double)v * (double)v;
    if (buildEt) ws[WS_ET + d * K_EMB + k] = v;   // Et[d][c], coalesced per d
  }
  ws[2048 + k] = (float)(0.5 * s);
}

// ---------------------------------------------------------------------------
// R9: barrier-free wave-autonomous kernel.
// Evidence: R8's bank-conflict fixes changed nothing (733.7 -> 744us), so LDS
// conflicts were never the wall. The wall is structural: shared-E-tile GEMM
// with 2 barriers/tile at 8 waves/CU + lockstep store tail. But E is 256KB =
// L2-resident; staging it through LDS is pure overhead (guide CM#7).
// New shape: wave = 16 samples x all 1024 codes (2 passes of 512).
//   a(k): 16 x-values from a wave-PRIVATE 4KB LDS transpose, read as 4
//         same-address ds_read_b128 (broadcast: no conflicts, no barriers).
//   b(k): each lane's 8 codes at dim k = 2 dwordx4 from Et in L2
//         (0.25 B/FMA -> ~20 TB/s aggregate < 34.5 TB/s L2 ceiling).
// Ping-pong unroll-by-2 prefetches k+1 while computing k (no reg copies).
// Exactness: per (s,c) a single fmaf chain, k ascending 0..63 -> bit-identical
// scores to R8; argmin = (score, lowest index) in-lane ascending fold + 6-step
// shfl_xor butterfly = JAX first-min semantics. No __syncthreads anywhere.
// ---------------------------------------------------------------------------

#define LOAD_A(D0,D1,D2,D3,row)                          \
  {                                                      \
    const float* xr_ = xrow + (row) * 16;                \
    D0 = *(const v4f*)(xr_ + 0);                         \
    D1 = *(const v4f*)(xr_ + 4);                         \
    D2 = *(const v4f*)(xr_ + 8);                         \
    D3 = *(const v4f*)(xr_ + 12);                        \
  }

#define LOAD_B(D0,D1,row)                                \
  {                                                      \
    const float* ep_ = et + (size_t)(row) * K_EMB;       \
    D0 = *(const v4f*)(ep_);                             \
    D1 = *(const v4f*)(ep_ + 4);                         \
  }

#define FMA_PHASE(A0_,A1_,A2_,A3_,B0_,B1_)                                   \
  {                                                                          \
    float as_[16] = {A0_.x,A0_.y,A0_.z,A0_.w, A1_.x,A1_.y,A1_.z,A1_.w,       \
                     A2_.x,A2_.y,A2_.z,A2_.w, A3_.x,A3_.y,A3_.z,A3_.w};      \
    float bs_[8]  = {B0_.x,B0_.y,B0_.z,B0_.w, B1_.x,B1_.y,B1_.z,B1_.w};      \
    _Pragma("unroll")                                                        \
    for (int s_ = 0; s_ < 16; ++s_)                                          \
      _Pragma("unroll")                                                      \
      for (int c_ = 0; c_ < 8; ++c_)                                         \
        acc[s_][c_] = fmaf(as_[s_], bs_[c_], acc[s_][c_]);                   \
  }

__global__ __launch_bounds__(256, 2) void k_gemm2(const float* __restrict__ xg,
                                                  const float* __restrict__ emb,
                                                  float* __restrict__ out,
                                                  float* __restrict__ ws) {
  __shared__ float Xw[4][64][16];          // 16 KB, one [64][16] slab per wave

  const int t = threadIdx.x;
  const int w = t >> 6;                    // wave id within block
  const int L = t & 63;                    // lane
  const int m0 = blockIdx.x * 64 + w * 16; // this wave's 16 samples

  // wave-local transpose stage: x[16][64] -> Xw[w][d][s]. No barrier needed:
  // only this wave touches Xw[w]; compiler orders via lgkmcnt.
  {
    const int s  = L & 15;
    const int dq = (L >> 4) * 16;
    const v4f* xp = (const v4f*)(xg + (size_t)(m0 + s) * D_EMB + dq);
    v4f r0 = xp[0], r1 = xp[1], r2 = xp[2], r3 = xp[3];
    #pragma unroll
    for (int e = 0; e < 4; ++e) {
      Xw[w][dq + 0  + e][s] = r0[e];
      Xw[w][dq + 4  + e][s] = r1[e];
      Xw[w][dq + 8  + e][s] = r2[e];
      Xw[w][dq + 12 + e][s] = r3[e];
    }
  }

  const float* xrow = &Xw[w][0][0];

  float best[16];
  int   bidx[16];
  #pragma unroll
  for (int s = 0; s < 16; ++s) { best[s] = 3.4e38f; bidx[s] = 0; }

  #pragma unroll 1
  for (int pass = 0; pass < 2; ++pass) {
    const int cb = pass * 512 + L * 8;     // this lane's 8 codes (ascending)
    const float* et = ws + WS_ET + cb;

    float acc[16][8];
    #pragma unroll
    for (int s = 0; s < 16; ++s)
      #pragma unroll
      for (int c = 0; c < 8; ++c) acc[s][c] = 0.0f;

    v4f A0, A1, A2, A3, B0, B1;            // current k
    v4f NA0, NA1, NA2, NA3, NB0, NB1;      // next k (prefetch)
    LOAD_A(A0, A1, A2, A3, 0)
    LOAD_B(B0, B1, 0)

    #pragma unroll 1
    for (int k2 = 0; k2 < 32; ++k2) {
      const int k = k2 * 2;
      // prefetch k+1 while computing k
      LOAD_A(NA0, NA1, NA2, NA3, k + 1)
      LOAD_B(NB0, NB1, k + 1)
      FMA_PHASE(A0, A1, A2, A3, B0, B1)
      // prefetch k+2 (clamped re-load of row 63 on last iter; unused)
      const int kn = (k2 < 31) ? (k + 2) : 63;
      LOAD_A(A0, A1, A2, A3, kn)
      LOAD_B(B0, B1, kn)
      FMA_PHASE(NA0, NA1, NA2, NA3, NB0, NB1)
    }

    // fold this code-half into the running argmin, code index ascending.
    // score = 0.5||e||^2 - x.e : same argmin as full distance (as in R8).
    const float* hp = ws + 2048 + cb;
    v4f h0 = *(const v4f*)(hp);
    v4f h1 = *(const v4f*)(hp + 4);
    float hs[8] = {h0.x, h0.y, h0.z, h0.w, h1.x, h1.y, h1.z, h1.w};
    #pragma unroll
    for (int c = 0; c < 8; ++c) {
      const int n = cb + c;
      #pragma unroll
      for (int s = 0; s < 16; ++s) {
        float sc = hs[c] - acc[s][c];
        bool lt = sc < best[s];            // strict <: lowest code wins ties
        best[s] = lt ? sc : best[s];
        bidx[s] = lt ? n  : bidx[s];
      }
    }
  }

  // cross-lane argmin butterfly; (score, idx) order reproduces first-min rule
  #pragma unroll
  for (int s = 0; s < 16; ++s) {
    float bs = best[s];
    int   bi = bidx[s];
    #pragma unroll
    for (int i = 0; i < 6; ++i) {
      int off = 32 >> i;
      float ob = __shfl_xor(bs, off, 64);
      int   oi = __shfl_xor(bi, off, 64);
      bool take = (ob < bs) || (ob == bs && oi < bi);
      bs = take ? ob : bs;
      bi = take ? oi : bi;
    }
    best[s] = bs;
    bidx[s] = bi;
  }

  // counts: one atomic per sample (lane s handles sample s)
  #pragma unroll
  for (int s = 0; s < 16; ++s)
    if (L == s) atomicAdd((unsigned int*)ws + bidx[s], 1u);

  // quantized + commitment loss (formulas identical to R8: q = x + (e - x))
  float lsum = 0.0f;
  #pragma unroll
  for (int s = 0; s < 16; ++s) {
    float xv = xg[(size_t)(m0 + s) * D_EMB + L];
    float ev = emb[(size_t)bidx[s] * D_EMB + L];
    float dx = ev - xv;
    lsum = fmaf(dx, dx, lsum);
    __builtin_nontemporal_store(xv + dx,
        out + QUANT_OFF + (size_t)(m0 + s) * D_EMB + L);
  }
  #pragma unroll
  for (int i = 0; i < 6; ++i) lsum += __shfl_xor(lsum, 32 >> i, 64);
  if (L == 0) atomicAdd(ws + 1024, lsum);

  // one-hot encodings: 16 rows x 1024; lane L covers v2f slots L+64q (coalesced)
  v2f* eb = (v2f*)(out + ENC_OFF);
  #pragma unroll
  for (int s = 0; s < 16; ++s) {
    int hit = bidx[s];
    int hc  = hit >> 1;
    v2f one; one.x = (hit & 1) ? 0.0f : 1.0f; one.y = (hit & 1) ? 1.0f : 0.0f;
    v2f zer; zer.x = 0.0f; zer.y = 0.0f;
    v2f* rowp = eb + (size_t)(m0 + s) * 512;
    #pragma unroll
    for (int q = 0; q < 8; ++q)
      __builtin_nontemporal_store((hc == L + 64 * q) ? one : zer,
                                  rowp + L + 64 * q);
  }
}

// ---------------------------------------------------------------------------
// Fallback path (R8 kernel, verbatim) — used only if ws_size can't hold Et.
// ---------------------------------------------------------------------------
__global__ __launch_bounds__(256, 2) void k_gemm(const float* __restrict__ xg,
                                                 const float* __restrict__ emb,
                                                 float* __restrict__ out,
                                                 float* __restrict__ ws) {
  __shared__ float Xs[64 * 128];                         // 32 KB: Xs[k][m]
  __shared__ union {
    struct { v4f A[64 * 17 + 1]; v4f B[64 * 17]; } es;   // 34.8 KB padded frags
    struct { float sc[2048]; int id[2048]; } red;        // 16 KB argmin scratch
  } U;
  __shared__ float hn_sh[1024];                          // 4 KB
  __shared__ int   ids[128];
  __shared__ float lred[256];

  const int t  = threadIdx.x;
  const int tx = t & 15;
  const int ty = t >> 4;
  const size_t m0 = (size_t)blockIdx.x * 128;

  const int colh = t >> 1;
  const int dqb  = (t & 1) * 32;
  const int qE   = t >> 4;
  const int ccE  = (t >> 1) & 3;
  float* frag = ((t >> 3) & 1) ? (float*)U.es.B : (float*)U.es.A;

  #pragma unroll
  for (int i = 0; i < 4; ++i) hn_sh[t + i * 256] = ws[2048 + t + i * 256];

  v4f pf[8];
  {
    const v4f* ep4 = (const v4f*)emb;
    #pragma unroll
    for (int i = 0; i < 8; ++i) pf[i] = ep4[8 * t + i];
  }

  {
    const v4f* xp4 = (const v4f*)(xg + m0 * 64);
    #pragma unroll
    for (int i = 0; i < 8; ++i) {
      v4f v = xp4[8 * t + i];
      int r0 = dqb + 4 * i;
      Xs[(r0 + 0) * 128 + colh] = v.x;
      Xs[(r0 + 1) * 128 + colh] = v.y;
      Xs[(r0 + 2) * 128 + colh] = v.z;
      Xs[(r0 + 3) * 128 + colh] = v.w;
    }
  }

  #pragma unroll
  for (int i = 0; i < 8; ++i) {
    v4f v = pf[i];
    int r0 = dqb + 4 * i;
    frag[((r0 + 0) * 17 + qE) * 4 + ccE] = v.x;
    frag[((r0 + 1) * 17 + qE) * 4 + ccE] = v.y;
    frag[((r0 + 2) * 17 + qE) * 4 + ccE] = v.z;
    frag[((r0 + 3) * 17 + qE) * 4 + ccE] = v.w;
  }
  __syncthreads();

  float best[8];
  int   bidx[8];
  #pragma unroll
  for (int i = 0; i < 8; ++i) { best[i] = 3.4e38f; bidx[i] = 0; }

  #pragma unroll 1
  for (int nt = 0; nt < 8; ++nt) {
    if (nt < 7) {
      const v4f* ep4 = (const v4f*)(emb + (size_t)(nt + 1) * 128 * 64);
      #pragma unroll
      for (int i = 0; i < 8; ++i) pf[i] = ep4[8 * t + i];
    }

    float acc[8][8];
    #pragma unroll
    for (int i = 0; i < 8; ++i)
      #pragma unroll
      for (int j = 0; j < 8; ++j) acc[i][j] = 0.f;

    #pragma unroll 4
    for (int k = 0; k < 64; ++k) {
      v4f a0 = *(const v4f*)&Xs[k * 128 + ty * 8];
      v4f a1 = *(const v4f*)&Xs[k * 128 + ty * 8 + 4];
      v4f b0 = U.es.A[k * 17 + tx];
      v4f b1 = U.es.B[k * 17 + tx];
      float a[8] = {a0.x, a0.y, a0.z, a0.w, a1.x, a1.y, a1.z, a1.w};
      float b[8] = {b0.x, b0.y, b0.z, b0.w, b1.x, b1.y, b1.z, b1.w};
      #pragma unroll
      for (int i = 0; i < 8; ++i)
        #pragma unroll
        for (int j = 0; j < 8; ++j)
          acc[i][j] = fmaf(a[i], b[j], acc[i][j]);
    }

    #pragma unroll
    for (int j = 0; j < 8; ++j) {
      int n = nt * 128 + tx * 8 + j;
      float h = hn_sh[n];
      #pragma unroll
      for (int i = 0; i < 8; ++i) {
        float sc = h - acc[i][j];
        bool c = sc < best[i];
        best[i] = c ? sc : best[i];
        bidx[i] = c ? n : bidx[i];
      }
    }
    __syncthreads();

    if (nt < 7) {
      #pragma unroll
      for (int i = 0; i < 8; ++i) {
        v4f v = pf[i];
        int r0 = dqb + 4 * i;
        frag[((r0 + 0) * 17 + qE) * 4 + ccE] = v.x;
        frag[((r0 + 1) * 17 + qE) * 4 + ccE] = v.y;
        frag[((r0 + 2) * 17 + qE) * 4 + ccE] = v.z;
        frag[((r0 + 3) * 17 + qE) * 4 + ccE] = v.w;
      }
    }
    __syncthreads();
  }

  #pragma unroll
  for (int i = 0; i < 8; ++i) {
    U.red.sc[t * 8 + i] = best[i];
    U.red.id[t * 8 + i] = bidx[i];
  }
  __syncthreads();

  if (t < 128) {
    int ty_r = t >> 3, i = t & 7;
    float b = 3.4e38f;
    int   bi = 0;
    #pragma unroll
    for (int xx = 0; xx < 16; ++xx) {
      float sg = U.red.sc[((ty_r * 16 + xx) * 8) + i];
      int   ig = U.red.id[((ty_r * 16 + xx) * 8) + i];
      if (sg < b) { b = sg; bi = ig; }
    }
    ids[t] = bi;
    atomicAdd((unsigned int*)ws + bi, 1u);
  }
  __syncthreads();

  float lsum = 0.0f;
  {
    float* qblk = out + QUANT_OFF + m0 * 64;
    const float* xblk = xg + m0 * 64;
    #pragma unroll 1
    for (int it = 0; it < 32; ++it) {
      int f = it * 256 + t;
      int r = f >> 6, d = f & 63;
      float ev = emb[((size_t)ids[r] << 6) + d];
      float xv = xblk[f];
      float dx = ev - xv;
      lsum = fmaf(dx, dx, lsum);
      __builtin_nontemporal_store(xv + dx, qblk + f);
    }
  }
  lred[t] = lsum;
  __syncthreads();
  #pragma unroll
  for (int off = 128; off > 0; off >>= 1) {
    if (t < off) lred[t] += lred[t + off];
    __syncthreads();
  }
  if (t == 0) atomicAdd(ws + 1024, lred[0]);

  v2f* eblk = (v2f*)(out + ENC_OFF) + m0 * 512;
  #pragma unroll 1
  for (int r = 0; r < 128; ++r) {
    int hit = ids[r];
    int hc  = hit >> 1;
    v2f one; one.x = (hit & 1) ? 0.0f : 1.0f; one.y = (hit & 1) ? 1.0f : 0.0f;
    v2f zer; zer.x = 0.0f; zer.y = 0.0f;
    v2f* rowp = eblk + (size_t)r * 512;
    __builtin_nontemporal_store((hc == t)       ? one : zer, rowp + t);
    __builtin_nontemporal_store((hc == t + 256) ? one : zer, rowp + t + 256);
  }
}

__global__ __launch_bounds__(256) void k_fin(float* __restrict__ out,
                                             const float* __restrict__ ws) {
  __shared__ float red[256];
  const unsigned int* counts = (const unsigned int*)ws;
  int t = threadIdx.x;
  float s = 0.0f;
  #pragma unroll
  for (int i = 0; i < 4; ++i) {
    float p = (float)counts[t + i * 256] * (1.0f / (float)N_IN);
    s += p * __logf(p + 1e-10f);
  }
  red[t] = s;
  __syncthreads();
  #pragma unroll
  for (int off = 128; off > 0; off >>= 1) {
    if (t < off) red[t] += red[t + off];
    __syncthreads();
  }
  if (t == 0) {
    out[PERP_OFF] = __expf(-red[0]);
    out[0] = 0.25f * ws[1024] * (1.0f / (float)(N_IN * D_EMB));
  }
}

extern "C" void kernel_launch(void* const* d_in, const int* in_sizes, int n_in,
                              void* d_out, int out_size, void* d_ws, size_t ws_size,
                              hipStream_t stream) {
  (void)in_sizes; (void)n_in; (void)out_size;
  const float* x   = (const float*)d_in[0];
  const float* emb = (const float*)d_in[1];
  float* out = (float*)d_out;
  float* ws  = (float*)d_ws;

  if (ws_size >= WS_NEED) {
    hipLaunchKernelGGL(k_prep,  dim3(4),        dim3(256), 0, stream, emb, ws, 1);
    hipLaunchKernelGGL(k_gemm2, dim3(N_IN / 64), dim3(256), 0, stream, x, emb, out, ws);
  } else {
    hipLaunchKernelGGL(k_prep,  dim3(4),        dim3(256), 0, stream, emb, ws, 0);
    hipLaunchKernelGGL(k_gemm,  dim3(1024),     dim3(256), 0, stream, x, emb, out, ws);
  }
  hipLaunchKernelGGL(k_fin, dim3(1), dim3(256), 0, stream, out, ws);
}

// Round 2
// 757.863 us; speedup vs baseline: 1.0036x; 1.0036x over previous
//
#include <hip/hip_runtime.h>

typedef float v2f __attribute__((ext_vector_type(2)));
typedef float v4f __attribute__((ext_vector_type(4)));

#define N_IN   131072
#define K_EMB  1024
#define D_EMB  64
#define QUANT_OFF 1
#define PERP_OFF  (1 + N_IN * D_EMB)      /* 8388609 */
#define ENC_OFF   (PERP_OFF + 1)          /* 8388610: %16==8 -> float2 stores only */

// R10: transposed codebook lives in static device memory -> no ws_size gate,
// no fallback path. Rewritten by k_prep every launch (re-poison safe).
__device__ float g_Et[D_EMB * K_EMB];     // Et[d][c]

// ws layout (4-byte units): [0..1023] counts (u32), [1024] loss (f32),
// [2048..3071] half squared norms (f32).  (R8 used this range and passed.)

__global__ __launch_bounds__(256) void k_prep(const float* __restrict__ emb,
                                              float* __restrict__ ws) {
  int k = blockIdx.x * 256 + threadIdx.x;  // grid=4 -> k in [0,1024)
  ((unsigned int*)ws)[k] = 0u;
  if (k == 0) ws[1024] = 0.0f;
  const float* e = emb + (size_t)k * D_EMB;
  double s = 0.0;
  #pragma unroll
  for (int d = 0; d < D_EMB; ++d) {
    float v = e[d];
    s += (double)v * (double)v;
    g_Et[d * K_EMB + k] = v;               // coalesced per d
  }
  ws[2048 + k] = (float)(0.5 * s);
}

// ---------------------------------------------------------------------------
// R10: barrier-free wave-autonomous argmin, sized for the 128-VGPR tier.
// R9 post-mortem: (a) fast path was gated on ws_size and may never have run;
// (b) acc[16][8]+ping-pong ~250 VGPRs under a 256 cap = spill risk at only
// 2 waves/SIMD. Occupancy tiers are hard steps (<=128 -> 4 waves/SIMD), so
// R10 halves the tile: wave = 8 samples x all 1024 codes (2 passes of 512),
// acc[8][8]=64 VGPRs, inner live-set ~115 -> 4 waves/SIMD, 4 blocks/CU.
//   a(k): 8 x-values via 2 same-address ds_read_b128 from a wave-private
//         [64][8] LDS transpose (broadcast: no conflicts, no barriers).
//   b(k): lane's 8 codes at dim k = 2 dwordx4 from g_Et (L2-resident 256KB).
// Per k: 64 FMA (128 issue cyc) vs ~6 mem insts -> ~90% FMA issue density.
// Exactness: per (s,c) one fmaf chain, k ascending -> same scores as R8/R9;
// argmin fold code-ascending + (score,idx) butterfly = JAX first-min rule.
// ---------------------------------------------------------------------------

#define LOAD_A(D0,D1,row)                                \
  {                                                      \
    const float* xr_ = xrow + (row) * 8;                 \
    D0 = *(const v4f*)(xr_ + 0);                         \
    D1 = *(const v4f*)(xr_ + 4);                         \
  }

#define LOAD_B(D0,D1,row)                                \
  {                                                      \
    const float* ep_ = et + (size_t)(row) * K_EMB;       \
    D0 = *(const v4f*)(ep_);                             \
    D1 = *(const v4f*)(ep_ + 4);                         \
  }

#define FMA_PHASE(A0_,A1_,B0_,B1_)                                           \
  {                                                                          \
    float as_[8] = {A0_.x,A0_.y,A0_.z,A0_.w, A1_.x,A1_.y,A1_.z,A1_.w};       \
    float bs_[8] = {B0_.x,B0_.y,B0_.z,B0_.w, B1_.x,B1_.y,B1_.z,B1_.w};       \
    _Pragma("unroll")                                                        \
    for (int s_ = 0; s_ < 8; ++s_)                                           \
      _Pragma("unroll")                                                      \
      for (int c_ = 0; c_ < 8; ++c_)                                         \
        acc[s_][c_] = fmaf(as_[s_], bs_[c_], acc[s_][c_]);                   \
  }

__global__ __launch_bounds__(256, 4) void k_gemm3(const float* __restrict__ xg,
                                                  const float* __restrict__ emb,
                                                  float* __restrict__ out,
                                                  float* __restrict__ ws) {
  __shared__ float Xw[4][64][8];           // 8 KB: wave-private [d][s] slabs

  const int t = threadIdx.x;
  const int w = t >> 6;                    // wave id within block
  const int L = t & 63;                    // lane
  const int m0 = blockIdx.x * 32 + w * 8;  // this wave's 8 samples

  // wave-local transpose: x[8][64] -> Xw[w][d][s]. Only this wave touches
  // Xw[w]; same-wave LDS ordering via lgkmcnt -> no barrier.
  {
    const int s  = L & 7;
    const int dq = (L >> 3) * 8;           // 8 lanes-groups x 8 dims
    const v4f* xp = (const v4f*)(xg + (size_t)(m0 + s) * D_EMB + dq);
    v4f r0 = xp[0], r1 = xp[1];
    #pragma unroll
    for (int e = 0; e < 4; ++e) {
      Xw[w][dq + 0 + e][s] = r0[e];
      Xw[w][dq + 4 + e][s] = r1[e];
    }
  }

  const float* xrow = &Xw[w][0][0];

  float best[8];
  int   bidx[8];
  #pragma unroll
  for (int s = 0; s < 8; ++s) { best[s] = 3.4e38f; bidx[s] = 0; }

  #pragma unroll 1
  for (int pass = 0; pass < 2; ++pass) {
    const int cb = pass * 512 + L * 8;     // this lane's 8 codes (ascending)
    const float* et = g_Et + cb;

    float acc[8][8];
    #pragma unroll
    for (int s = 0; s < 8; ++s)
      #pragma unroll
      for (int c = 0; c < 8; ++c) acc[s][c] = 0.0f;

    v4f A0, A1, B0, B1;                    // current k
    v4f NA0, NA1, NB0, NB1;                // next k (prefetch)
    LOAD_A(A0, A1, 0)
    LOAD_B(B0, B1, 0)

    #pragma unroll 1
    for (int k2 = 0; k2 < 32; ++k2) {
      const int k = k2 * 2;
      LOAD_A(NA0, NA1, k + 1)              // prefetch k+1 under compute of k
      LOAD_B(NB0, NB1, k + 1)
      FMA_PHASE(A0, A1, B0, B1)
      const int kn = (k2 < 31) ? (k + 2) : 63;  // clamped dummy on last iter
      LOAD_A(A0, A1, kn)
      LOAD_B(B0, B1, kn)
      FMA_PHASE(NA0, NA1, NB0, NB1)
    }

    // fold this code-half into the running argmin, code index ascending.
    // score = 0.5||e||^2 - x.e : same argmin as full distance.
    const float* hp = ws + 2048 + cb;
    v4f h0 = *(const v4f*)(hp);
    v4f h1 = *(const v4f*)(hp + 4);
    float hs[8] = {h0.x, h0.y, h0.z, h0.w, h1.x, h1.y, h1.z, h1.w};
    #pragma unroll
    for (int c = 0; c < 8; ++c) {
      const int n = cb + c;
      #pragma unroll
      for (int s = 0; s < 8; ++s) {
        float sc = hs[c] - acc[s][c];
        bool lt = sc < best[s];            // strict <: lowest code wins ties
        best[s] = lt ? sc : best[s];
        bidx[s] = lt ? n  : bidx[s];
      }
    }
  }

  // cross-lane argmin butterfly; (score, idx) order = first-min rule
  #pragma unroll
  for (int s = 0; s < 8; ++s) {
    float bs = best[s];
    int   bi = bidx[s];
    #pragma unroll
    for (int i = 0; i < 6; ++i) {
      int off = 32 >> i;
      float ob = __shfl_xor(bs, off, 64);
      int   oi = __shfl_xor(bi, off, 64);
      bool take = (ob < bs) || (ob == bs && oi < bi);
      bs = take ? ob : bs;
      bi = take ? oi : bi;
    }
    best[s] = bs;
    bidx[s] = bi;
  }

  // counts: one atomic per sample
  #pragma unroll
  for (int s = 0; s < 8; ++s)
    if (L == s) atomicAdd((unsigned int*)ws + bidx[s], 1u);

  // quantized + commitment loss (q = x + (e - x): ref order)
  float lsum = 0.0f;
  #pragma unroll
  for (int s = 0; s < 8; ++s) {
    float xv = xg[(size_t)(m0 + s) * D_EMB + L];
    float ev = emb[(size_t)bidx[s] * D_EMB + L];
    float dx = ev - xv;
    lsum = fmaf(dx, dx, lsum);
    __builtin_nontemporal_store(xv + dx,
        out + QUANT_OFF + (size_t)(m0 + s) * D_EMB + L);
  }
  #pragma unroll
  for (int i = 0; i < 6; ++i) lsum += __shfl_xor(lsum, 32 >> i, 64);
  if (L == 0) atomicAdd(ws + 1024, lsum);

  // one-hot encodings: 8 rows x 1024; lane L covers v2f slots L+64q (coalesced)
  v2f* eb = (v2f*)(out + ENC_OFF);
  #pragma unroll
  for (int s = 0; s < 8; ++s) {
    int hit = bidx[s];
    int hc  = hit >> 1;
    v2f one; one.x = (hit & 1) ? 0.0f : 1.0f; one.y = (hit & 1) ? 1.0f : 0.0f;
    v2f zer; zer.x = 0.0f; zer.y = 0.0f;
    v2f* rowp = eb + (size_t)(m0 + s) * 512;
    #pragma unroll
    for (int q = 0; q < 8; ++q)
      __builtin_nontemporal_store((hc == L + 64 * q) ? one : zer,
                                  rowp + L + 64 * q);
  }
}

__global__ __launch_bounds__(256) void k_fin(float* __restrict__ out,
                                             const float* __restrict__ ws) {
  __shared__ float red[256];
  const unsigned int* counts = (const unsigned int*)ws;
  int t = threadIdx.x;
  float s = 0.0f;
  #pragma unroll
  for (int i = 0; i < 4; ++i) {
    float p = (float)counts[t + i * 256] * (1.0f / (float)N_IN);
    s += p * __logf(p + 1e-10f);
  }
  red[t] = s;
  __syncthreads();
  #pragma unroll
  for (int off = 128; off > 0; off >>= 1) {
    if (t < off) red[t] += red[t + off];
    __syncthreads();
  }
  if (t == 0) {
    out[PERP_OFF] = __expf(-red[0]);
    out[0] = 0.25f * ws[1024] * (1.0f / (float)(N_IN * D_EMB));
  }
}

extern "C" void kernel_launch(void* const* d_in, const int* in_sizes, int n_in,
                              void* d_out, int out_size, void* d_ws, size_t ws_size,
                              hipStream_t stream) {
  (void)in_sizes; (void)n_in; (void)out_size; (void)ws_size;
  const float* x   = (const float*)d_in[0];
  const float* emb = (const float*)d_in[1];
  float* out = (float*)d_out;
  float* ws  = (float*)d_ws;

  hipLaunchKernelGGL(k_prep,  dim3(4),           dim3(256), 0, stream, emb, ws);
  hipLaunchKernelGGL(k_gemm3, dim3(N_IN / 32),   dim3(256), 0, stream, x, emb, out, ws);
  hipLaunchKernelGGL(k_fin,   dim3(1),           dim3(256), 0, stream, out, ws);
}